// Round 2
// baseline (652.487 us; speedup 1.0000x reference)
//
#include <hip/hip_runtime.h>
#include <math.h>

typedef short short8 __attribute__((ext_vector_type(8)));
typedef float floatx4 __attribute__((ext_vector_type(4)));

#define W_UNSUP 0.2f
#define NB_BCE 256
#define NSPLIT 8
// exp(5*acc - 5) = exp2(acc*7.2134752 - 7.2134752)
#define L2E5 7.2134752f

static __device__ __forceinline__ unsigned short f2bf(float f) {
  unsigned int u = __float_as_uint(f);
  u += 0x7FFFu + ((u >> 16) & 1u);
  return (unsigned short)(u >> 16);
}
static __device__ __forceinline__ float bf2f(unsigned short u) {
  return __uint_as_float(((unsigned int)u) << 16);
}

__device__ __forceinline__ float block_sum256(float v) {
  __shared__ float sh[4];
  for (int m = 1; m <= 32; m <<= 1) v += __shfl_xor(v, m);
  __syncthreads();
  if ((threadIdx.x & 63) == 0) sh[threadIdx.x >> 6] = v;
  __syncthreads();
  return sh[0] + sh[1] + sh[2] + sh[3];
}

// Detect train_mask storage: 0 = int32 {0,1}, 1 = float32 {0,1.0f}, 2 = raw bytes
__global__ void detect_kernel(const unsigned int* __restrict__ w, int nw, int* __restrict__ flag) {
  __shared__ int s_int, s_flt;
  if (threadIdx.x == 0) { s_int = 1; s_flt = 1; }
  __syncthreads();
  for (int i = threadIdx.x; i < nw; i += blockDim.x) {
    unsigned int x = w[i];
    if (x != 0u && x != 1u) s_int = 0;
    if (x != 0u && x != 0x3F800000u) s_flt = 0;
  }
  __syncthreads();
  if (threadIdx.x == 0) *flag = s_int ? 0 : (s_flt ? 1 : 2);
}

__global__ __launch_bounds__(256) void bce_kernel(
    const float* __restrict__ fused, const float* __restrict__ viewl,
    const float* __restrict__ labels, const void* __restrict__ maskp,
    const int* __restrict__ flagp, float* __restrict__ partials, int N, int V) {
  const int flag = *flagp;
  float cnt = 0.f, sm = 0.f;
  float sv[8];
  for (int v = 0; v < 8; v++) sv[v] = 0.f;
  const int Vc = V > 8 ? 8 : V;
  for (int i = blockIdx.x * blockDim.x + threadIdx.x; i < N; i += gridDim.x * blockDim.x) {
    bool m;
    if (flag == 0)      m = ((const int*)maskp)[i] != 0;
    else if (flag == 1) m = ((const float*)maskp)[i] != 0.0f;
    else                m = ((const unsigned char*)maskp)[i] != 0;
    if (!m) continue;
    float y = labels[i];
    cnt += 1.0f;
    float x = fused[i];
    sm += fmaxf(x, 0.f) - x * y + log1pf(__expf(-fabsf(x)));
    for (int v = 0; v < Vc; v++) {
      float xv = viewl[(size_t)v * N + i];
      sv[v] += fmaxf(xv, 0.f) - xv * y + log1pf(__expf(-fabsf(xv)));
    }
  }
  float tot = block_sum256(cnt);
  if (threadIdx.x == 0) partials[blockIdx.x * 16 + 0] = tot;
  tot = block_sum256(sm);
  if (threadIdx.x == 0) partials[blockIdx.x * 16 + 1] = tot;
  for (int v = 0; v < Vc; v++) {
    tot = block_sum256(sv[v]);
    if (threadIdx.x == 0) partials[blockIdx.x * 16 + 2 + v] = tot;
  }
}

// Wave-per-row gather: bf16 cast (sup) / normalize+cast (uns); per-row diag sim d = 5*||z||^2.
__global__ __launch_bounds__(256) void gather_kernel(
    const float* __restrict__ proj, const int* __restrict__ pos_idx,
    const int* __restrict__ neg_idx, const int* __restrict__ unl_idx,
    unsigned short* __restrict__ zsup, unsigned short* __restrict__ zuns,
    float* __restrict__ dsup, float* __restrict__ duns,
    int N, int D, int V, int P, int Msup, int Muns) {
  const int prob = blockIdx.y;
  const int wave = threadIdx.x >> 6, lane = threadIdx.x & 63;
  const int r = blockIdx.x * 4 + wave;
  const int M = prob ? Muns : Msup;
  if (r >= M) return;
  const int l = r / V, v = r - l * V;
  const int idx = prob ? unl_idx[l] : (l < P ? pos_idx[l] : neg_idx[l - P]);
  const float* src = proj + ((size_t)v * N + (size_t)idx) * D;
  float ss = 0.f;
  for (int d0 = lane * 4; d0 < D; d0 += 256) {
    float4 x = *(const float4*)(src + d0);
    ss += x.x * x.x + x.y * x.y + x.z * x.z + x.w * x.w;
  }
  for (int m = 1; m <= 32; m <<= 1) ss += __shfl_xor(ss, m);
  if (prob == 0) {
    for (int d0 = lane * 4; d0 < D; d0 += 256) {
      float4 x = *(const float4*)(src + d0);
      unsigned short o[4] = {f2bf(x.x), f2bf(x.y), f2bf(x.z), f2bf(x.w)};
      *(unsigned long long*)(zsup + (size_t)r * D + d0) = *(unsigned long long*)o;
    }
    if (lane == 0) dsup[r] = ss * 5.0f;
  } else {
    const float sc = 1.0f / (sqrtf(ss) + 1e-8f);
    for (int d0 = lane * 4; d0 < D; d0 += 256) {
      float4 x = *(const float4*)(src + d0);
      unsigned short o[4] = {f2bf(x.x * sc), f2bf(x.y * sc), f2bf(x.z * sc), f2bf(x.w * sc)};
      *(unsigned long long*)(zuns + (size_t)r * D + d0) = *(unsigned long long*)o;
    }
    if (lane == 0) duns[r] = ss * sc * sc * 5.0f;
  }
}

// Column sums: Ssup[2][D] (label blocks, atomicAdd into zeroed buf), Suns[U][D] (per node).
__global__ __launch_bounds__(256) void sums_kernel(
    const unsigned short* __restrict__ zsup, const unsigned short* __restrict__ zuns,
    float* __restrict__ Ssup, float* __restrict__ Suns,
    int D, int V, int PV, int Msup, int U) {
  const int b = blockIdx.x;
  if (b < 32) {
    const int lab = b >> 4, sub = b & 15;
    const int start = lab ? PV : 0, end = lab ? Msup : PV;
    for (int d = threadIdx.x; d < D; d += 256) {
      float acc = 0.f;
      for (int r = start + sub; r < end; r += 16) acc += bf2f(zsup[(size_t)r * D + d]);
      atomicAdd(&Ssup[lab * D + d], acc);
    }
  } else {
    const int n = b - 32;
    if (n >= U) return;
    for (int d = threadIdx.x; d < D; d += 256) {
      float acc = 0.f;
      for (int v = 0; v < V; v++) acc += bf2f(zuns[((size_t)n * V + v) * D + d]);
      Suns[(size_t)n * D + d] = acc;
    }
  }
}

// sim kernel: per block 64 rows (A resident, 4 fragment sets/wave), each wave owns a
// private 16-col strip of the 64-col LDS tile (no cross-wave B re-reads).
// Accumulates E_row = sum_j exp2(7.213*(sim/5) - 7.213) = sum_j exp(sim - 5), incl diag.
// D==256 assumed (K-loop fully unrolled). Requires M % 64 == 0 unless CHECK.
template <bool CHECK>
__global__ __launch_bounds__(256, 2) void sim_kernel(
    const unsigned short* __restrict__ zsup, const unsigned short* __restrict__ zuns,
    float* __restrict__ Esup, float* __restrict__ Euns, int Msup, int Muns) {
  const int prob = blockIdx.z;
  const unsigned short* __restrict__ z = prob ? zuns : zsup;
  float* __restrict__ Ep = prob ? Euns : Esup;
  const int M = prob ? Muns : Msup;
  const int tid = threadIdx.x, lane = tid & 63, wave = tid >> 6;
  const int q = lane >> 4, n16 = lane & 15;
  const int rowBase = blockIdx.y * 64;
  if (rowBase >= M) return;

  // A fragments: set s covers rows rowBase+16s..+15. A[m=lane&15][k=q*8+j].
  short8 afrag[4][8];
#pragma unroll
  for (int s = 0; s < 4; s++) {
    int arow = rowBase + s * 16 + n16;
    if (CHECK && arow >= M) arow = M - 1;
    const unsigned short* zr = z + (size_t)arow * 256 + q * 8;
#pragma unroll
    for (int ks = 0; ks < 8; ks++) afrag[s][ks] = *(const short8*)(zr + ks * 32);
  }

  float Eacc[4][4] = {};
  // 64 col-rows x 256 K, +8 bf16 pad -> row stride 132 dwords == 4 (mod 32): 2-way, free.
  __shared__ __align__(16) unsigned short lds[64 * 264];

  const int tiles = (M + 63) >> 6;
  const int tps = (tiles + NSPLIT - 1) / NSPLIT;
  const int tBeg = blockIdx.x * tps;
  const int tEnd = min(tBeg + tps, tiles);

  for (int tI = tBeg; tI < tEnd; tI++) {
    const int c0 = tI * 64;
    __syncthreads();
#pragma unroll
    for (int cc = 0; cc < 8; cc++) {
      int chunk = cc * 256 + tid;  // 2048 x 16B
      int rrow = chunk >> 5, off = (chunk & 31) * 8;
      int gcol = c0 + rrow;
      short8 vv = {};
      if (!CHECK || gcol < M) vv = *(const short8*)(z + (size_t)gcol * 256 + off);
      *(short8*)(&lds[rrow * 264 + off]) = vv;
    }
    __syncthreads();

    const unsigned short* bp = &lds[(wave * 16 + n16) * 264 + q * 8];
    floatx4 a0 = {}, a1 = {}, a2 = {}, a3 = {};
#pragma unroll
    for (int ks = 0; ks < 8; ks++) {
      short8 bfrag = *(const short8*)(bp + ks * 32);
      a0 = __builtin_amdgcn_mfma_f32_16x16x32_bf16(afrag[0][ks], bfrag, a0, 0, 0, 0);
      a1 = __builtin_amdgcn_mfma_f32_16x16x32_bf16(afrag[1][ks], bfrag, a1, 0, 0, 0);
      a2 = __builtin_amdgcn_mfma_f32_16x16x32_bf16(afrag[2][ks], bfrag, a2, 0, 0, 0);
      a3 = __builtin_amdgcn_mfma_f32_16x16x32_bf16(afrag[3][ks], bfrag, a3, 0, 0, 0);
    }
    const int j = c0 + wave * 16 + n16;
    const bool jok = !CHECK || (j < M);
#pragma unroll
    for (int r = 0; r < 4; r++) {
      float e0 = exp2f(fmaf(a0[r], L2E5, -L2E5));
      float e1 = exp2f(fmaf(a1[r], L2E5, -L2E5));
      float e2 = exp2f(fmaf(a2[r], L2E5, -L2E5));
      float e3 = exp2f(fmaf(a3[r], L2E5, -L2E5));
      if (jok) { Eacc[0][r] += e0; Eacc[1][r] += e1; Eacc[2][r] += e2; Eacc[3][r] += e3; }
    }
  }

  // C row for set s = rowBase + 16s + q*4 + r; reduce over the quad's 16 lanes (cols).
#pragma unroll
  for (int s = 0; s < 4; s++) {
#pragma unroll
    for (int r = 0; r < 4; r++) {
      float e = Eacc[s][r];
      e += __shfl_xor(e, 1); e += __shfl_xor(e, 2);
      e += __shfl_xor(e, 4); e += __shfl_xor(e, 8);
      const int row = rowBase + s * 16 + q * 4 + r;
      if (n16 == 0 && (!CHECK || row < M)) atomicAdd(&Ep[row], e);
    }
  }
}

// Wave-per-row: B = 5*dot(z_row, S_block); per-anchor term; atomicAdd into sums[prob].
__global__ __launch_bounds__(256) void anchor_kernel(
    const unsigned short* __restrict__ zsup, const unsigned short* __restrict__ zuns,
    const float* __restrict__ Esup, const float* __restrict__ Euns,
    const float* __restrict__ dsup, const float* __restrict__ duns,
    const float* __restrict__ Ssup, const float* __restrict__ Suns,
    float* __restrict__ sums, int Msup, int Muns, int PV, int P, int NEG, int V, int D) {
  const int prob = blockIdx.y;
  const int wave = threadIdx.x >> 6, lane = threadIdx.x & 63;
  const int row = blockIdx.x * 4 + wave;
  const int M = prob ? Muns : Msup;
  if (row >= M) return;
  const unsigned short* z = prob ? zuns : zsup;
  const float* S = prob ? &Suns[(size_t)(row / V) * D] : &Ssup[(row < PV ? 0 : 1) * D];
  float dp = 0.f;
  for (int d0 = lane * 4; d0 < D; d0 += 256) {
    const unsigned short* zr = z + (size_t)row * D + d0;
    float4 s4 = *(const float4*)(S + d0);
    dp += bf2f(zr[0]) * s4.x + bf2f(zr[1]) * s4.y + bf2f(zr[2]) * s4.z + bf2f(zr[3]) * s4.w;
  }
  for (int m = 1; m <= 32; m <<= 1) dp += __shfl_xor(dp, m);
  if (lane == 0) {
    const float E = prob ? Euns[row] : Esup[row];
    const float d = prob ? duns[row] : dsup[row];
    const float ediag = exp2f(fmaf(d, 1.4426950f, -L2E5));  // exp(d-5)
    const float B = 5.0f * dp;                               // includes diagonal
    const float pc = prob ? (float)(V - 1) : (float)((row < PV ? P : NEG) * V - 1);
    const float term = logf(E - ediag) + 5.0f - (B - d) / pc;
    atomicAdd(&sums[prob], term);
  }
}

__global__ __launch_bounds__(256) void final_kernel(
    const float* __restrict__ partials, const float* __restrict__ sums,
    int Msup, int Muns, int V, float* __restrict__ out) {
  float cnt = 0.f, sm = 0.f, sv = 0.f;
  const int Vc = V > 8 ? 8 : V;
  for (int b = threadIdx.x; b < NB_BCE; b += 256) {
    cnt += partials[b * 16 + 0];
    sm += partials[b * 16 + 1];
    for (int v = 0; v < Vc; v++) sv += partials[b * 16 + 2 + v];
  }
  cnt = block_sum256(cnt);
  sm = block_sum256(sm);
  sv = block_sum256(sv);
  if (threadIdx.x == 0) {
    const float denomC = fmaxf(cnt, 1.0f);
    const float main_loss = sm / denomC;
    const float view_loss = (sv / denomC) / (float)V;
    const float sup_loss = sums[0] / (float)Msup;
    const float unsup_loss = sums[1] / (float)Muns;
    out[0] = main_loss + view_loss + sup_loss + W_UNSUP * unsup_loss;
    out[1] = main_loss;
    out[2] = view_loss;
    out[3] = sup_loss;
    out[4] = unsup_loss;
  }
}

extern "C" void kernel_launch(void* const* d_in, const int* in_sizes, int n_in,
                              void* d_out, int out_size, void* d_ws, size_t ws_size,
                              hipStream_t stream) {
  const float* fused  = (const float*)d_in[0];
  const float* viewl  = (const float*)d_in[1];
  const float* proj   = (const float*)d_in[2];
  const float* labels = (const float*)d_in[3];
  const void*  maskp  = d_in[4];
  const int* pos_idx  = (const int*)d_in[5];
  const int* neg_idx  = (const int*)d_in[6];
  const int* unl_idx  = (const int*)d_in[7];

  const int N = in_sizes[0];
  const int V = in_sizes[1] / N;
  const int D = in_sizes[2] / in_sizes[1];  // 256
  const int P = in_sizes[5];
  const int NEG = in_sizes[6];
  const int U = in_sizes[7];
  const int L = P + NEG;
  const int Msup = L * V;
  const int Muns = U * V;
  const int PV = P * V;
  const int Mmax = Msup > Muns ? Msup : Muns;

  char* ws = (char*)d_ws;
  size_t off = 0;
  auto alloc = [&](size_t bytes) { size_t o = off; off += (bytes + 255) & ~(size_t)255; return o; };
  const size_t o_flag = alloc(4);
  const size_t o_part = alloc((size_t)NB_BCE * 16 * 4);
  const size_t o_zsup = alloc((size_t)Msup * D * 2);
  const size_t o_zuns = alloc((size_t)Muns * D * 2);
  const size_t o_dsup = alloc((size_t)Msup * 4);
  const size_t o_duns = alloc((size_t)Muns * 4);
  const size_t o_Suns = alloc((size_t)U * D * 4);
  // zero-initialized region (one memset covers [o_Esup, o_sums+8)):
  const size_t o_Esup = alloc((size_t)Msup * 4);
  const size_t o_Euns = alloc((size_t)Muns * 4);
  const size_t o_Ssup = alloc((size_t)2 * D * 4);
  const size_t o_sums = alloc(8);
  const size_t zero_beg = o_Esup, zero_end = o_sums + 256;

  int* flag = (int*)(ws + o_flag);
  float* partials = (float*)(ws + o_part);
  unsigned short* zsup = (unsigned short*)(ws + o_zsup);
  unsigned short* zuns = (unsigned short*)(ws + o_zuns);
  float* dsup = (float*)(ws + o_dsup);
  float* duns = (float*)(ws + o_duns);
  float* Suns = (float*)(ws + o_Suns);
  float* Esup = (float*)(ws + o_Esup);
  float* Euns = (float*)(ws + o_Euns);
  float* Ssup = (float*)(ws + o_Ssup);
  float* sums = (float*)(ws + o_sums);

  hipMemsetAsync(ws + zero_beg, 0, zero_end - zero_beg, stream);

  int nw = N / 4 < 256 ? N / 4 : 256;
  detect_kernel<<<1, 256, 0, stream>>>((const unsigned int*)maskp, nw, flag);
  bce_kernel<<<NB_BCE, 256, 0, stream>>>(fused, viewl, labels, maskp, flag, partials, N, V);

  dim3 ggrid((Mmax + 3) / 4, 2);
  gather_kernel<<<ggrid, 256, 0, stream>>>(proj, pos_idx, neg_idx, unl_idx,
                                           zsup, zuns, dsup, duns, N, D, V, P, Msup, Muns);

  sums_kernel<<<32 + U, 256, 0, stream>>>(zsup, zuns, Ssup, Suns, D, V, PV, Msup, U);

  dim3 sgrid(NSPLIT, (Mmax + 63) / 64, 2);
  const bool need_check = ((Msup & 63) != 0) || ((Muns & 63) != 0);
  if (need_check)
    sim_kernel<true><<<sgrid, 256, 0, stream>>>(zsup, zuns, Esup, Euns, Msup, Muns);
  else
    sim_kernel<false><<<sgrid, 256, 0, stream>>>(zsup, zuns, Esup, Euns, Msup, Muns);

  dim3 agrid((Mmax + 3) / 4, 2);
  anchor_kernel<<<agrid, 256, 0, stream>>>(zsup, zuns, Esup, Euns, dsup, duns,
                                           Ssup, Suns, sums, Msup, Muns, PV, P, NEG, V, D);

  final_kernel<<<1, 256, 0, stream>>>(partials, sums, Msup, Muns, V, (float*)d_out);
}

// Round 3
// 613.777 us; speedup vs baseline: 1.0631x; 1.0631x over previous
//
#include <hip/hip_runtime.h>
#include <math.h>

typedef short short8 __attribute__((ext_vector_type(8)));
typedef float floatx4 __attribute__((ext_vector_type(4)));

#define W_UNSUP 0.2f
#define NB_BCE 256
#define NSPLIT 8
#define NSUP_BLOCKS 256
// exp(5*acc - 5) = exp2(acc*7.2134752 - 7.2134752)
#define L2E5 7.2134752f

static __device__ __forceinline__ unsigned short f2bf(float f) {
  unsigned int u = __float_as_uint(f);
  u += 0x7FFFu + ((u >> 16) & 1u);
  return (unsigned short)(u >> 16);
}
static __device__ __forceinline__ float bf2f(unsigned short u) {
  return __uint_as_float(((unsigned int)u) << 16);
}

__device__ __forceinline__ float block_sum256(float v) {
  __shared__ float sh[4];
  for (int m = 1; m <= 32; m <<= 1) v += __shfl_xor(v, m);
  __syncthreads();
  if ((threadIdx.x & 63) == 0) sh[threadIdx.x >> 6] = v;
  __syncthreads();
  return sh[0] + sh[1] + sh[2] + sh[3];
}

__global__ __launch_bounds__(256) void zero_kernel(float* __restrict__ p, int n) {
  for (int i = blockIdx.x * 256 + threadIdx.x; i < n; i += gridDim.x * 256) p[i] = 0.f;
}

// BCE with inline mask-dtype detection (0=int32 {0,1}, 1=float32 {0,1.0f}, 2=bytes).
__global__ __launch_bounds__(256) void bce_kernel(
    const float* __restrict__ fused, const float* __restrict__ viewl,
    const float* __restrict__ labels, const void* __restrict__ maskp,
    float* __restrict__ partials, int N, int V) {
  __shared__ int s_int, s_flt;
  if (threadIdx.x == 0) { s_int = 1; s_flt = 1; }
  __syncthreads();
  {
    const unsigned int* w = (const unsigned int*)maskp;
    int nw = N / 4; if (nw > 1024) nw = 1024; if (nw < 1) nw = 1;
    for (int i = threadIdx.x; i < nw; i += 256) {
      unsigned int x = w[i];
      if (x != 0u && x != 1u) s_int = 0;
      if (x != 0u && x != 0x3F800000u) s_flt = 0;
    }
  }
  __syncthreads();
  const int flag = s_int ? 0 : (s_flt ? 1 : 2);

  float cnt = 0.f, sm = 0.f;
  float sv[8];
  for (int v = 0; v < 8; v++) sv[v] = 0.f;
  const int Vc = V > 8 ? 8 : V;
  for (int i = blockIdx.x * blockDim.x + threadIdx.x; i < N; i += gridDim.x * blockDim.x) {
    bool m;
    if (flag == 0)      m = ((const int*)maskp)[i] != 0;
    else if (flag == 1) m = ((const float*)maskp)[i] != 0.0f;
    else                m = ((const unsigned char*)maskp)[i] != 0;
    if (!m) continue;
    float y = labels[i];
    cnt += 1.0f;
    float x = fused[i];
    sm += fmaxf(x, 0.f) - x * y + log1pf(__expf(-fabsf(x)));
    for (int v = 0; v < Vc; v++) {
      float xv = viewl[(size_t)v * N + i];
      sv[v] += fmaxf(xv, 0.f) - xv * y + log1pf(__expf(-fabsf(xv)));
    }
  }
  float tot = block_sum256(cnt);
  if (threadIdx.x == 0) partials[blockIdx.x * 16 + 0] = tot;
  tot = block_sum256(sm);
  if (threadIdx.x == 0) partials[blockIdx.x * 16 + 1] = tot;
  for (int v = 0; v < Vc; v++) {
    tot = block_sum256(sv[v]);
    if (threadIdx.x == 0) partials[blockIdx.x * 16 + 2 + v] = tot;
  }
}

// Wave-per-row gather: bf16 cast (sup) / normalize+cast (uns); per-row diag sim d = 5*||z||^2.
__global__ __launch_bounds__(256) void gather_kernel(
    const float* __restrict__ proj, const int* __restrict__ pos_idx,
    const int* __restrict__ neg_idx, const int* __restrict__ unl_idx,
    unsigned short* __restrict__ zsup, unsigned short* __restrict__ zuns,
    float* __restrict__ dsup, float* __restrict__ duns,
    int N, int D, int V, int P, int Msup, int Muns) {
  const int prob = blockIdx.y;
  const int wave = threadIdx.x >> 6, lane = threadIdx.x & 63;
  const int r = blockIdx.x * 4 + wave;
  const int M = prob ? Muns : Msup;
  if (r >= M) return;
  const int l = r / V, v = r - l * V;
  const int idx = prob ? unl_idx[l] : (l < P ? pos_idx[l] : neg_idx[l - P]);
  const float* src = proj + ((size_t)v * N + (size_t)idx) * D;
  float ss = 0.f;
  for (int d0 = lane * 4; d0 < D; d0 += 256) {
    float4 x = *(const float4*)(src + d0);
    ss += x.x * x.x + x.y * x.y + x.z * x.z + x.w * x.w;
  }
  for (int m = 1; m <= 32; m <<= 1) ss += __shfl_xor(ss, m);
  if (prob == 0) {
    for (int d0 = lane * 4; d0 < D; d0 += 256) {
      float4 x = *(const float4*)(src + d0);
      unsigned short o[4] = {f2bf(x.x), f2bf(x.y), f2bf(x.z), f2bf(x.w)};
      *(unsigned long long*)(zsup + (size_t)r * D + d0) = *(unsigned long long*)o;
    }
    if (lane == 0) dsup[r] = ss * 5.0f;
  } else {
    const float sc = 1.0f / (sqrtf(ss) + 1e-8f);
    for (int d0 = lane * 4; d0 < D; d0 += 256) {
      float4 x = *(const float4*)(src + d0);
      unsigned short o[4] = {f2bf(x.x * sc), f2bf(x.y * sc), f2bf(x.z * sc), f2bf(x.w * sc)};
      *(unsigned long long*)(zuns + (size_t)r * D + d0) = *(unsigned long long*)o;
    }
    if (lane == 0) duns[r] = ss * sc * sc * 5.0f;
  }
}

// Column sums: Ssup[2][D] (label blocks, atomicAdd into zeroed buf), Suns[U][D] (per node).
__global__ __launch_bounds__(256) void sums_kernel(
    const unsigned short* __restrict__ zsup, const unsigned short* __restrict__ zuns,
    float* __restrict__ Ssup, float* __restrict__ Suns,
    int D, int V, int PV, int Msup, int U) {
  const int b = blockIdx.x;
  if (b < NSUP_BLOCKS) {
    const int lab = b >> 7, sub = b & 127;
    const int start = lab ? PV : 0, end = lab ? Msup : PV;
    for (int d = threadIdx.x; d < D; d += 256) {
      float acc = 0.f;
      for (int r = start + sub; r < end; r += 128) acc += bf2f(zsup[(size_t)r * D + d]);
      atomicAdd(&Ssup[lab * D + d], acc);
    }
  } else {
    const int n = b - NSUP_BLOCKS;
    if (n >= U) return;
    for (int d = threadIdx.x; d < D; d += 256) {
      float acc = 0.f;
      for (int v = 0; v < V; v++) acc += bf2f(zuns[((size_t)n * V + v) * D + d]);
      Suns[(size_t)n * D + d] = acc;
    }
  }
}

// sim: block = 64 rows x 64 cols per tile. Wave w: rows rowBase+32*(w>>1)+{0..31}
// (2 register-resident A-fragment sets = 64 VGPRs), cols 32*(w&1)+{0..31} of the
// LDS tile. E_row += sum_j exp(sim - 5) (incl. diag; subtracted in anchor).
// D==256 assumed; requires M % 64 == 0 unless CHECK.
template <bool CHECK>
__global__ __launch_bounds__(256) void sim_kernel(
    const unsigned short* __restrict__ zsup, const unsigned short* __restrict__ zuns,
    float* __restrict__ Esup, float* __restrict__ Euns, int Msup, int Muns) {
  const int prob = blockIdx.z;
  const unsigned short* __restrict__ z = prob ? zuns : zsup;
  float* __restrict__ Ep = prob ? Euns : Esup;
  const int M = prob ? Muns : Msup;
  const int tid = threadIdx.x, lane = tid & 63, wave = tid >> 6;
  const int q = lane >> 4, n16 = lane & 15;
  const int rowHalf = wave >> 1, colHalf = wave & 1;
  const int rowBase = blockIdx.y * 64;
  if (rowBase >= M) return;

  // A fragments: set s covers rows rowBase+32*rowHalf+16*s+{0..15}. A[m=n16][k=q*8+j].
  short8 afrag[2][8];
#pragma unroll
  for (int s = 0; s < 2; s++) {
    int arow = rowBase + rowHalf * 32 + s * 16 + n16;
    if (CHECK && arow >= M) arow = M - 1;
    const unsigned short* zr = z + (size_t)arow * 256 + q * 8;
#pragma unroll
    for (int ks = 0; ks < 8; ks++) afrag[s][ks] = *(const short8*)(zr + ks * 32);
  }

  float Eacc[2][2][4] = {};  // [set][cb][reg]
  // 64 col-rows x 256 K, +8 bf16 pad -> row stride 132 dwords == 4 (mod 32): 2-way, free.
  __shared__ __align__(16) unsigned short lds[64 * 264];

  const int tiles = (M + 63) >> 6;
  const int tps = (tiles + NSPLIT - 1) / NSPLIT;
  const int tBeg = blockIdx.x * tps;
  const int tEnd = min(tBeg + tps, tiles);

  for (int tI = tBeg; tI < tEnd; tI++) {
    const int c0 = tI * 64;
    __syncthreads();
#pragma unroll
    for (int cc = 0; cc < 8; cc++) {
      int chunk = cc * 256 + tid;  // 2048 x 16B
      int rrow = chunk >> 5, off = (chunk & 31) * 8;
      int gcol = c0 + rrow;
      short8 vv = {};
      if (!CHECK || gcol < M) vv = *(const short8*)(z + (size_t)gcol * 256 + off);
      *(short8*)(&lds[rrow * 264 + off]) = vv;
    }
    __syncthreads();

#pragma unroll
    for (int cb = 0; cb < 2; cb++) {
      const unsigned short* bp = &lds[(colHalf * 32 + cb * 16 + n16) * 264 + q * 8];
      floatx4 a0 = {}, a1 = {};
#pragma unroll
      for (int ks = 0; ks < 8; ks++) {
        short8 bfrag = *(const short8*)(bp + ks * 32);
        a0 = __builtin_amdgcn_mfma_f32_16x16x32_bf16(afrag[0][ks], bfrag, a0, 0, 0, 0);
        a1 = __builtin_amdgcn_mfma_f32_16x16x32_bf16(afrag[1][ks], bfrag, a1, 0, 0, 0);
      }
      const int j = c0 + colHalf * 32 + cb * 16 + n16;
      const bool jok = !CHECK || (j < M);
#pragma unroll
      for (int r = 0; r < 4; r++) {
        float e0 = exp2f(fmaf(a0[r], L2E5, -L2E5));
        float e1 = exp2f(fmaf(a1[r], L2E5, -L2E5));
        if (jok) { Eacc[0][cb][r] += e0; Eacc[1][cb][r] += e1; }
      }
    }
  }

  // C row for set s = rowBase + 32*rowHalf + 16*s + q*4 + r; reduce cb pair, then
  // the quad's 16 lanes (columns), one atomic per row per (block, colHalf).
#pragma unroll
  for (int s = 0; s < 2; s++) {
#pragma unroll
    for (int r = 0; r < 4; r++) {
      float e = Eacc[s][0][r] + Eacc[s][1][r];
      e += __shfl_xor(e, 1); e += __shfl_xor(e, 2);
      e += __shfl_xor(e, 4); e += __shfl_xor(e, 8);
      const int row = rowBase + rowHalf * 32 + s * 16 + q * 4 + r;
      if (n16 == 0 && (!CHECK || row < M)) atomicAdd(&Ep[row], e);
    }
  }
}

// Wave-per-row: B = 5*dot(z_row, S_block); per-anchor term; atomicAdd into sums[prob].
__global__ __launch_bounds__(256) void anchor_kernel(
    const unsigned short* __restrict__ zsup, const unsigned short* __restrict__ zuns,
    const float* __restrict__ Esup, const float* __restrict__ Euns,
    const float* __restrict__ dsup, const float* __restrict__ duns,
    const float* __restrict__ Ssup, const float* __restrict__ Suns,
    float* __restrict__ sums, int Msup, int Muns, int PV, int P, int NEG, int V, int D) {
  const int prob = blockIdx.y;
  const int wave = threadIdx.x >> 6, lane = threadIdx.x & 63;
  const int row = blockIdx.x * 4 + wave;
  const int M = prob ? Muns : Msup;
  if (row >= M) return;
  const unsigned short* z = prob ? zuns : zsup;
  const float* S = prob ? &Suns[(size_t)(row / V) * D] : &Ssup[(row < PV ? 0 : 1) * D];
  float dp = 0.f;
  for (int d0 = lane * 4; d0 < D; d0 += 256) {
    const unsigned short* zr = z + (size_t)row * D + d0;
    float4 s4 = *(const float4*)(S + d0);
    dp += bf2f(zr[0]) * s4.x + bf2f(zr[1]) * s4.y + bf2f(zr[2]) * s4.z + bf2f(zr[3]) * s4.w;
  }
  for (int m = 1; m <= 32; m <<= 1) dp += __shfl_xor(dp, m);
  if (lane == 0) {
    const float E = prob ? Euns[row] : Esup[row];
    const float d = prob ? duns[row] : dsup[row];
    const float ediag = exp2f(fmaf(d, 1.4426950f, -L2E5));  // exp(d-5)
    const float B = 5.0f * dp;                               // includes diagonal
    const float pc = prob ? (float)(V - 1) : (float)((row < PV ? P : NEG) * V - 1);
    const float term = logf(E - ediag) + 5.0f - (B - d) / pc;
    atomicAdd(&sums[prob], term);
  }
}

__global__ __launch_bounds__(256) void final_kernel(
    const float* __restrict__ partials, const float* __restrict__ sums,
    int Msup, int Muns, int V, float* __restrict__ out) {
  float cnt = 0.f, sm = 0.f, sv = 0.f;
  const int Vc = V > 8 ? 8 : V;
  for (int b = threadIdx.x; b < NB_BCE; b += 256) {
    cnt += partials[b * 16 + 0];
    sm += partials[b * 16 + 1];
    for (int v = 0; v < Vc; v++) sv += partials[b * 16 + 2 + v];
  }
  cnt = block_sum256(cnt);
  sm = block_sum256(sm);
  sv = block_sum256(sv);
  if (threadIdx.x == 0) {
    const float denomC = fmaxf(cnt, 1.0f);
    const float main_loss = sm / denomC;
    const float view_loss = (sv / denomC) / (float)V;
    const float sup_loss = sums[0] / (float)Msup;
    const float unsup_loss = sums[1] / (float)Muns;
    out[0] = main_loss + view_loss + sup_loss + W_UNSUP * unsup_loss;
    out[1] = main_loss;
    out[2] = view_loss;
    out[3] = sup_loss;
    out[4] = unsup_loss;
  }
}

extern "C" void kernel_launch(void* const* d_in, const int* in_sizes, int n_in,
                              void* d_out, int out_size, void* d_ws, size_t ws_size,
                              hipStream_t stream) {
  const float* fused  = (const float*)d_in[0];
  const float* viewl  = (const float*)d_in[1];
  const float* proj   = (const float*)d_in[2];
  const float* labels = (const float*)d_in[3];
  const void*  maskp  = d_in[4];
  const int* pos_idx  = (const int*)d_in[5];
  const int* neg_idx  = (const int*)d_in[6];
  const int* unl_idx  = (const int*)d_in[7];

  const int N = in_sizes[0];
  const int V = in_sizes[1] / N;
  const int D = in_sizes[2] / in_sizes[1];  // 256
  const int P = in_sizes[5];
  const int NEG = in_sizes[6];
  const int U = in_sizes[7];
  const int L = P + NEG;
  const int Msup = L * V;
  const int Muns = U * V;
  const int PV = P * V;
  const int Mmax = Msup > Muns ? Msup : Muns;

  char* ws = (char*)d_ws;
  size_t off = 0;
  auto alloc = [&](size_t bytes) { size_t o = off; off += (bytes + 255) & ~(size_t)255; return o; };
  const size_t o_part = alloc((size_t)NB_BCE * 16 * 4);
  const size_t o_zsup = alloc((size_t)Msup * D * 2);
  const size_t o_zuns = alloc((size_t)Muns * D * 2);
  const size_t o_dsup = alloc((size_t)Msup * 4);
  const size_t o_duns = alloc((size_t)Muns * 4);
  const size_t o_Suns = alloc((size_t)U * D * 4);
  // zero-initialized region (one zero_kernel covers [o_Esup, zero_end)):
  const size_t o_Esup = alloc((size_t)Msup * 4);
  const size_t o_Euns = alloc((size_t)Muns * 4);
  const size_t o_Ssup = alloc((size_t)2 * D * 4);
  const size_t o_sums = alloc(8);
  const size_t zero_beg = o_Esup, zero_end = o_sums + 256;

  float* partials = (float*)(ws + o_part);
  unsigned short* zsup = (unsigned short*)(ws + o_zsup);
  unsigned short* zuns = (unsigned short*)(ws + o_zuns);
  float* dsup = (float*)(ws + o_dsup);
  float* duns = (float*)(ws + o_duns);
  float* Suns = (float*)(ws + o_Suns);
  float* Esup = (float*)(ws + o_Esup);
  float* Euns = (float*)(ws + o_Euns);
  float* Ssup = (float*)(ws + o_Ssup);
  float* sums = (float*)(ws + o_sums);

  const int nzero = (int)((zero_end - zero_beg) / 4);
  zero_kernel<<<64, 256, 0, stream>>>((float*)(ws + zero_beg), nzero);

  bce_kernel<<<NB_BCE, 256, 0, stream>>>(fused, viewl, labels, maskp, partials, N, V);

  dim3 ggrid((Mmax + 3) / 4, 2);
  gather_kernel<<<ggrid, 256, 0, stream>>>(proj, pos_idx, neg_idx, unl_idx,
                                           zsup, zuns, dsup, duns, N, D, V, P, Msup, Muns);

  sums_kernel<<<NSUP_BLOCKS + U, 256, 0, stream>>>(zsup, zuns, Ssup, Suns, D, V, PV, Msup, U);

  dim3 sgrid(NSPLIT, (Mmax + 63) / 64, 2);
  const bool need_check = ((Msup & 63) != 0) || ((Muns & 63) != 0);
  if (need_check)
    sim_kernel<true><<<sgrid, 256, 0, stream>>>(zsup, zuns, Esup, Euns, Msup, Muns);
  else
    sim_kernel<false><<<sgrid, 256, 0, stream>>>(zsup, zuns, Esup, Euns, Msup, Muns);

  dim3 agrid((Mmax + 3) / 4, 2);
  anchor_kernel<<<agrid, 256, 0, stream>>>(zsup, zuns, Esup, Euns, dsup, duns,
                                           Ssup, Suns, sums, Msup, Muns, PV, P, NEG, V, D);

  final_kernel<<<1, 256, 0, stream>>>(partials, sums, Msup, Muns, V, (float*)d_out);
}

// Round 4
// 501.399 us; speedup vs baseline: 1.3013x; 1.2241x over previous
//
#include <hip/hip_runtime.h>
#include <math.h>

typedef short short8 __attribute__((ext_vector_type(8)));
typedef float floatx4 __attribute__((ext_vector_type(4)));

#define W_UNSUP 0.2f
#define NB_BCE 256
#define NSPLIT 16
#define NSUP_BLOCKS 32
// exp(5*acc - 5) = exp2(acc*7.2134752 - 7.2134752)
#define L2E5 7.2134752f

static __device__ __forceinline__ unsigned short f2bf(float f) {
  unsigned int u = __float_as_uint(f);
  u += 0x7FFFu + ((u >> 16) & 1u);
  return (unsigned short)(u >> 16);
}
static __device__ __forceinline__ float bf2f(unsigned short u) {
  return __uint_as_float(((unsigned int)u) << 16);
}

__device__ __forceinline__ float block_sum256(float v) {
  __shared__ float sh[4];
  for (int m = 1; m <= 32; m <<= 1) v += __shfl_xor(v, m);
  __syncthreads();
  if ((threadIdx.x & 63) == 0) sh[threadIdx.x >> 6] = v;
  __syncthreads();
  return sh[0] + sh[1] + sh[2] + sh[3];
}

// BCE with inline mask-dtype detection (0=int32 {0,1}, 1=float32 {0,1.0f}, 2=bytes).
__global__ __launch_bounds__(256) void bce_kernel(
    const float* __restrict__ fused, const float* __restrict__ viewl,
    const float* __restrict__ labels, const void* __restrict__ maskp,
    float* __restrict__ partials, int N, int V) {
  __shared__ int s_int, s_flt;
  if (threadIdx.x == 0) { s_int = 1; s_flt = 1; }
  __syncthreads();
  {
    const unsigned int* w = (const unsigned int*)maskp;
    int nw = N / 4; if (nw > 1024) nw = 1024; if (nw < 1) nw = 1;
    for (int i = threadIdx.x; i < nw; i += 256) {
      unsigned int x = w[i];
      if (x != 0u && x != 1u) s_int = 0;
      if (x != 0u && x != 0x3F800000u) s_flt = 0;
    }
  }
  __syncthreads();
  const int flag = s_int ? 0 : (s_flt ? 1 : 2);

  float cnt = 0.f, sm = 0.f;
  float sv[8];
  for (int v = 0; v < 8; v++) sv[v] = 0.f;
  const int Vc = V > 8 ? 8 : V;
  for (int i = blockIdx.x * blockDim.x + threadIdx.x; i < N; i += gridDim.x * blockDim.x) {
    bool m;
    if (flag == 0)      m = ((const int*)maskp)[i] != 0;
    else if (flag == 1) m = ((const float*)maskp)[i] != 0.0f;
    else                m = ((const unsigned char*)maskp)[i] != 0;
    if (!m) continue;
    float y = labels[i];
    cnt += 1.0f;
    float x = fused[i];
    sm += fmaxf(x, 0.f) - x * y + log1pf(__expf(-fabsf(x)));
    for (int v = 0; v < Vc; v++) {
      float xv = viewl[(size_t)v * N + i];
      sv[v] += fmaxf(xv, 0.f) - xv * y + log1pf(__expf(-fabsf(xv)));
    }
  }
  float tot = block_sum256(cnt);
  if (threadIdx.x == 0) partials[blockIdx.x * 16 + 0] = tot;
  tot = block_sum256(sm);
  if (threadIdx.x == 0) partials[blockIdx.x * 16 + 1] = tot;
  for (int v = 0; v < Vc; v++) {
    tot = block_sum256(sv[v]);
    if (threadIdx.x == 0) partials[blockIdx.x * 16 + 2 + v] = tot;
  }
}

// Wave-per-row gather: bf16 cast (sup) / normalize+cast (uns); diag d = 5*||z||^2.
// Block (0, prob=0) additionally zeroes Ssup (sums_kernel accumulates into it).
__global__ __launch_bounds__(256) void gather_kernel(
    const float* __restrict__ proj, const int* __restrict__ pos_idx,
    const int* __restrict__ neg_idx, const int* __restrict__ unl_idx,
    unsigned short* __restrict__ zsup, unsigned short* __restrict__ zuns,
    float* __restrict__ dsup, float* __restrict__ duns, float* __restrict__ Ssup,
    int N, int D, int V, int P, int Msup, int Muns) {
  const int prob = blockIdx.y;
  if (prob == 0 && blockIdx.x == 0) {
    for (int d = threadIdx.x; d < 2 * D; d += 256) Ssup[d] = 0.f;
  }
  const int wave = threadIdx.x >> 6, lane = threadIdx.x & 63;
  const int r = blockIdx.x * 4 + wave;
  const int M = prob ? Muns : Msup;
  if (r >= M) return;
  const int l = r / V, v = r - l * V;
  const int idx = prob ? unl_idx[l] : (l < P ? pos_idx[l] : neg_idx[l - P]);
  const float* src = proj + ((size_t)v * N + (size_t)idx) * D;
  float ss = 0.f;
  for (int d0 = lane * 4; d0 < D; d0 += 256) {
    float4 x = *(const float4*)(src + d0);
    ss += x.x * x.x + x.y * x.y + x.z * x.z + x.w * x.w;
  }
  for (int m = 1; m <= 32; m <<= 1) ss += __shfl_xor(ss, m);
  if (prob == 0) {
    for (int d0 = lane * 4; d0 < D; d0 += 256) {
      float4 x = *(const float4*)(src + d0);
      unsigned short o[4] = {f2bf(x.x), f2bf(x.y), f2bf(x.z), f2bf(x.w)};
      *(unsigned long long*)(zsup + (size_t)r * D + d0) = *(unsigned long long*)o;
    }
    if (lane == 0) dsup[r] = ss * 5.0f;
  } else {
    const float sc = 1.0f / (sqrtf(ss) + 1e-8f);
    for (int d0 = lane * 4; d0 < D; d0 += 256) {
      float4 x = *(const float4*)(src + d0);
      unsigned short o[4] = {f2bf(x.x * sc), f2bf(x.y * sc), f2bf(x.z * sc), f2bf(x.w * sc)};
      *(unsigned long long*)(zuns + (size_t)r * D + d0) = *(unsigned long long*)o;
    }
    if (lane == 0) duns[r] = ss * sc * sc * 5.0f;
  }
}

// Column sums: Ssup[2][D] (16 blocks/label, strided, few spread atomics),
// Suns[U][D] (direct writes, one block per node).
__global__ __launch_bounds__(256) void sums_kernel(
    const unsigned short* __restrict__ zsup, const unsigned short* __restrict__ zuns,
    float* __restrict__ Ssup, float* __restrict__ Suns,
    int D, int V, int PV, int Msup, int U) {
  const int b = blockIdx.x;
  if (b < NSUP_BLOCKS) {
    const int lab = b >> 4, sub = b & 15;
    const int start = lab ? PV : 0, end = lab ? Msup : PV;
    for (int d = threadIdx.x; d < D; d += 256) {
      float acc = 0.f;
      for (int r = start + sub; r < end; r += 16) acc += bf2f(zsup[(size_t)r * D + d]);
      atomicAdd(&Ssup[lab * D + d], acc);
    }
  } else {
    const int n = b - NSUP_BLOCKS;
    if (n >= U) return;
    for (int d = threadIdx.x; d < D; d += 256) {
      float acc = 0.f;
      for (int v = 0; v < V; v++) acc += bf2f(zuns[((size_t)n * V + v) * D + d]);
      Suns[(size_t)n * D + d] = acc;
    }
  }
}

// sim: block = 64 rows x 64 cols/tile. Wave w: rows rowBase+32*(w>>1)+{0..31}
// (2 A-fragment sets resident), cols 32*(w&1)+{0..31} of the LDS tile.
// E partials per col-split written non-atomically to Ep[split*M+row];
// colHalf pair combined through LDS. D==256; M%64==0 unless CHECK.
template <bool CHECK>
__global__ __launch_bounds__(256) void sim_kernel(
    const unsigned short* __restrict__ zsup, const unsigned short* __restrict__ zuns,
    float* __restrict__ Esup, float* __restrict__ Euns, int Msup, int Muns) {
  const int prob = blockIdx.z;
  const unsigned short* __restrict__ z = prob ? zuns : zsup;
  float* __restrict__ Ep = prob ? Euns : Esup;
  const int M = prob ? Muns : Msup;
  const int tid = threadIdx.x, lane = tid & 63, wave = tid >> 6;
  const int q = lane >> 4, n16 = lane & 15;
  const int rowHalf = wave >> 1, colHalf = wave & 1;
  const int rowBase = blockIdx.y * 64;
  if (rowBase >= M) return;

  short8 afrag[2][8];
#pragma unroll
  for (int s = 0; s < 2; s++) {
    int arow = rowBase + rowHalf * 32 + s * 16 + n16;
    if (CHECK && arow >= M) arow = M - 1;
    const unsigned short* zr = z + (size_t)arow * 256 + q * 8;
#pragma unroll
    for (int ks = 0; ks < 8; ks++) afrag[s][ks] = *(const short8*)(zr + ks * 32);
  }

  float Eacc[2][2][4] = {};  // [set][cb][reg]
  // 64 col-rows x 256 K, +8 bf16 pad -> stride 132 dwords == 4 (mod 32): balanced.
  __shared__ __align__(16) unsigned short lds[64 * 264];

  const int tiles = (M + 63) >> 6;
  const int tps = (tiles + NSPLIT - 1) / NSPLIT;
  const int tBeg = blockIdx.x * tps;
  const int tEnd = min(tBeg + tps, tiles);

  for (int tI = tBeg; tI < tEnd; tI++) {
    const int c0 = tI * 64;
    __syncthreads();
#pragma unroll
    for (int cc = 0; cc < 8; cc++) {
      int chunk = cc * 256 + tid;  // 2048 x 16B
      int rrow = chunk >> 5, off = (chunk & 31) * 8;
      int gcol = c0 + rrow;
      short8 vv = {};
      if (!CHECK || gcol < M) vv = *(const short8*)(z + (size_t)gcol * 256 + off);
      *(short8*)(&lds[rrow * 264 + off]) = vv;
    }
    __syncthreads();

#pragma unroll
    for (int cb = 0; cb < 2; cb++) {
      const unsigned short* bp = &lds[(colHalf * 32 + cb * 16 + n16) * 264 + q * 8];
      floatx4 a0 = {}, a1 = {};
#pragma unroll
      for (int ks = 0; ks < 8; ks++) {
        short8 bfrag = *(const short8*)(bp + ks * 32);
        a0 = __builtin_amdgcn_mfma_f32_16x16x32_bf16(afrag[0][ks], bfrag, a0, 0, 0, 0);
        a1 = __builtin_amdgcn_mfma_f32_16x16x32_bf16(afrag[1][ks], bfrag, a1, 0, 0, 0);
      }
      const int j = c0 + colHalf * 32 + cb * 16 + n16;
      const bool jok = !CHECK || (j < M);
#pragma unroll
      for (int r = 0; r < 4; r++) {
        float e0 = exp2f(fmaf(a0[r], L2E5, -L2E5));
        float e1 = exp2f(fmaf(a1[r], L2E5, -L2E5));
        if (jok) { Eacc[0][cb][r] += e0; Eacc[1][cb][r] += e1; }
      }
    }
  }

  // Reduce: cb pair, then quad's 16 lanes; combine the two colHalf waves via LDS.
  float red[2][4];
#pragma unroll
  for (int s = 0; s < 2; s++) {
#pragma unroll
    for (int r = 0; r < 4; r++) {
      float e = Eacc[s][0][r] + Eacc[s][1][r];
      e += __shfl_xor(e, 1); e += __shfl_xor(e, 2);
      e += __shfl_xor(e, 4); e += __shfl_xor(e, 8);
      red[s][r] = e;  // valid on n16==0 lanes
    }
  }
  __syncthreads();
  float* fsh = (float*)lds;
  if (colHalf == 1 && n16 == 0) {
#pragma unroll
    for (int s = 0; s < 2; s++)
#pragma unroll
      for (int r = 0; r < 4; r++) fsh[rowHalf * 32 + s * 16 + q * 4 + r] = red[s][r];
  }
  __syncthreads();
  if (colHalf == 0 && n16 == 0) {
#pragma unroll
    for (int s = 0; s < 2; s++)
#pragma unroll
      for (int r = 0; r < 4; r++) {
        const int rl = rowHalf * 32 + s * 16 + q * 4 + r;
        const int row = rowBase + rl;
        if (!CHECK || row < M) Ep[(size_t)blockIdx.x * M + row] = red[s][r] + fsh[rl];
      }
  }
}

// Wave-per-row: B = 5*dot(z_row, S_block); sum NSPLIT E-partials in-register;
// per-row term -> block reduction -> termblk[prob*gridX + bx]. No atomics.
__global__ __launch_bounds__(256) void anchor_kernel(
    const unsigned short* __restrict__ zsup, const unsigned short* __restrict__ zuns,
    const float* __restrict__ Esup, const float* __restrict__ Euns,
    const float* __restrict__ dsup, const float* __restrict__ duns,
    const float* __restrict__ Ssup, const float* __restrict__ Suns,
    float* __restrict__ termblk, int gridX,
    int Msup, int Muns, int PV, int P, int NEG, int V, int D) {
  const int prob = blockIdx.y;
  const int wave = threadIdx.x >> 6, lane = threadIdx.x & 63;
  const int row = blockIdx.x * 4 + wave;
  const int M = prob ? Muns : Msup;
  float term = 0.f;
  if (row < M) {
    const unsigned short* z = prob ? zuns : zsup;
    const float* Ep = prob ? Euns : Esup;
    const float* S = prob ? &Suns[(size_t)(row / V) * D] : &Ssup[(row < PV ? 0 : 1) * D];
    float dp = 0.f;
    for (int d0 = lane * 4; d0 < D; d0 += 256) {
      const unsigned short* zr = z + (size_t)row * D + d0;
      float4 s4 = *(const float4*)(S + d0);
      dp += bf2f(zr[0]) * s4.x + bf2f(zr[1]) * s4.y + bf2f(zr[2]) * s4.z + bf2f(zr[3]) * s4.w;
    }
    for (int m = 1; m <= 32; m <<= 1) dp += __shfl_xor(dp, m);
    float Ei = (lane < NSPLIT) ? Ep[(size_t)lane * M + row] : 0.f;
    Ei += __shfl_xor(Ei, 1); Ei += __shfl_xor(Ei, 2);
    Ei += __shfl_xor(Ei, 4); Ei += __shfl_xor(Ei, 8);
    if (lane == 0) {
      const float d = prob ? duns[row] : dsup[row];
      const float ediag = exp2f(fmaf(d, 1.4426950f, -L2E5));  // exp(d-5)
      const float B = 5.0f * dp;                               // includes diagonal
      const float pc = prob ? (float)(V - 1) : (float)((row < PV ? P : NEG) * V - 1);
      term = logf(Ei - ediag) + 5.0f - (B - d) / pc;
    }
  }
  float bs = block_sum256((lane == 0) ? term : 0.f);
  if (threadIdx.x == 0) termblk[(size_t)prob * gridX + blockIdx.x] = bs;
}

__global__ __launch_bounds__(256) void final_kernel(
    const float* __restrict__ partials, const float* __restrict__ termblk, int gridX,
    int Msup, int Muns, int V, float* __restrict__ out) {
  float cnt = 0.f, sm = 0.f, sv = 0.f;
  const int Vc = V > 8 ? 8 : V;
  for (int b = threadIdx.x; b < NB_BCE; b += 256) {
    cnt += partials[b * 16 + 0];
    sm += partials[b * 16 + 1];
    for (int v = 0; v < Vc; v++) sv += partials[b * 16 + 2 + v];
  }
  float tsup = 0.f, tuns = 0.f;
  for (int b = threadIdx.x; b < gridX; b += 256) {
    tsup += termblk[b];
    tuns += termblk[(size_t)gridX + b];
  }
  cnt = block_sum256(cnt);
  sm = block_sum256(sm);
  sv = block_sum256(sv);
  tsup = block_sum256(tsup);
  tuns = block_sum256(tuns);
  if (threadIdx.x == 0) {
    const float denomC = fmaxf(cnt, 1.0f);
    const float main_loss = sm / denomC;
    const float view_loss = (sv / denomC) / (float)V;
    const float sup_loss = tsup / (float)Msup;
    const float unsup_loss = tuns / (float)Muns;
    out[0] = main_loss + view_loss + sup_loss + W_UNSUP * unsup_loss;
    out[1] = main_loss;
    out[2] = view_loss;
    out[3] = sup_loss;
    out[4] = unsup_loss;
  }
}

extern "C" void kernel_launch(void* const* d_in, const int* in_sizes, int n_in,
                              void* d_out, int out_size, void* d_ws, size_t ws_size,
                              hipStream_t stream) {
  const float* fused  = (const float*)d_in[0];
  const float* viewl  = (const float*)d_in[1];
  const float* proj   = (const float*)d_in[2];
  const float* labels = (const float*)d_in[3];
  const void*  maskp  = d_in[4];
  const int* pos_idx  = (const int*)d_in[5];
  const int* neg_idx  = (const int*)d_in[6];
  const int* unl_idx  = (const int*)d_in[7];

  const int N = in_sizes[0];
  const int V = in_sizes[1] / N;
  const int D = in_sizes[2] / in_sizes[1];  // 256
  const int P = in_sizes[5];
  const int NEG = in_sizes[6];
  const int U = in_sizes[7];
  const int L = P + NEG;
  const int Msup = L * V;
  const int Muns = U * V;
  const int PV = P * V;
  const int Mmax = Msup > Muns ? Msup : Muns;
  const int gridX = (Mmax + 3) / 4;

  char* ws = (char*)d_ws;
  size_t off = 0;
  auto alloc = [&](size_t bytes) { size_t o = off; off += (bytes + 255) & ~(size_t)255; return o; };
  const size_t o_part = alloc((size_t)NB_BCE * 16 * 4);
  const size_t o_zsup = alloc((size_t)Msup * D * 2);
  const size_t o_zuns = alloc((size_t)Muns * D * 2);
  const size_t o_dsup = alloc((size_t)Msup * 4);
  const size_t o_duns = alloc((size_t)Muns * 4);
  const size_t o_Suns = alloc((size_t)U * D * 4);
  const size_t o_Ssup = alloc((size_t)2 * D * 4);
  const size_t o_Esup = alloc((size_t)NSPLIT * Msup * 4);
  const size_t o_Euns = alloc((size_t)NSPLIT * Muns * 4);
  const size_t o_term = alloc((size_t)2 * gridX * 4);

  float* partials = (float*)(ws + o_part);
  unsigned short* zsup = (unsigned short*)(ws + o_zsup);
  unsigned short* zuns = (unsigned short*)(ws + o_zuns);
  float* dsup = (float*)(ws + o_dsup);
  float* duns = (float*)(ws + o_duns);
  float* Suns = (float*)(ws + o_Suns);
  float* Ssup = (float*)(ws + o_Ssup);
  float* Esup = (float*)(ws + o_Esup);
  float* Euns = (float*)(ws + o_Euns);
  float* termblk = (float*)(ws + o_term);

  bce_kernel<<<NB_BCE, 256, 0, stream>>>(fused, viewl, labels, maskp, partials, N, V);

  dim3 ggrid(gridX, 2);
  gather_kernel<<<ggrid, 256, 0, stream>>>(proj, pos_idx, neg_idx, unl_idx,
                                           zsup, zuns, dsup, duns, Ssup, N, D, V, P, Msup, Muns);

  sums_kernel<<<NSUP_BLOCKS + U, 256, 0, stream>>>(zsup, zuns, Ssup, Suns, D, V, PV, Msup, U);

  dim3 sgrid(NSPLIT, (Mmax + 63) / 64, 2);
  const bool need_check = ((Msup & 63) != 0) || ((Muns & 63) != 0);
  if (need_check)
    sim_kernel<true><<<sgrid, 256, 0, stream>>>(zsup, zuns, Esup, Euns, Msup, Muns);
  else
    sim_kernel<false><<<sgrid, 256, 0, stream>>>(zsup, zuns, Esup, Euns, Msup, Muns);

  dim3 agrid(gridX, 2);
  anchor_kernel<<<agrid, 256, 0, stream>>>(zsup, zuns, Esup, Euns, dsup, duns,
                                           Ssup, Suns, termblk, gridX,
                                           Msup, Muns, PV, P, NEG, V, D);

  final_kernel<<<1, 256, 0, stream>>>(partials, termblk, gridX, Msup, Muns, V, (float*)d_out);
}